// Round 2
// baseline (533.896 us; speedup 1.0000x reference)
//
#include <hip/hip_runtime.h>

using f16   = _Float16;
using f16x8 = __attribute__((ext_vector_type(8))) _Float16;
using f32x4 = __attribute__((ext_vector_type(4))) float;

#define DEVI __device__ __forceinline__

namespace {
// 32KB LDS, two 16KB regions, time-multiplexed:
//  R_A: Q [64][128] swzA  ->  P (waves 0,1; 8KB each)  ->  V^T [128][64] swzB
//  R_B: K [64][128] swzA  ->  P (waves 2,3; 8KB each)  ->  O [64][128] swzA
constexpr int R_A = 0;
constexpr int R_B = 16384;
constexpr float LOGIT_MAX_C = 4.6051701859880914f;  // log(100)
constexpr float L2E = 1.4426950408889634f;
}

// XOR swizzle: conflict-free ds_read_b128 on 256B/128B row-major tiles (G4).
DEVI int swzA(int row, int b) { return (row << 8) + (b ^ ((row & 7) << 4)); }  // 256B rows
DEVI int swzB(int row, int b) { return (row << 7) + (b ^ ((row & 7) << 4)); }  // 128B rows

DEVI f16x8 ldA(const char* base, int row, int k0) {   // [*, 128] f16 tile
  return *reinterpret_cast<const f16x8*>(base + swzA(row, k0 << 1));
}
DEVI f16x8 ldB(const char* base, int row, int k0) {   // [*, 64] f16 tile
  return *reinterpret_cast<const f16x8*>(base + swzB(row, k0 << 1));
}
// 8 consecutive fp32 from a [*,128] row-major global matrix -> f16x8 (in-flight cvt)
DEVI f16x8 ld_g8(const float* __restrict__ G, int row, int k0) {
  const float4* p = reinterpret_cast<const float4*>(G + row * 128 + k0);
  float4 a = p[0], c = p[1];
  f16x8 r;
  r[0] = (f16)a.x; r[1] = (f16)a.y; r[2] = (f16)a.z; r[3] = (f16)a.w;
  r[4] = (f16)c.x; r[5] = (f16)c.y; r[6] = (f16)c.z; r[7] = (f16)c.w;
  return r;
}

// out[64, 32w..32w+32) = X @ W^T (+bias) -> dst [64][128] swzA (wave-private cols)
// X read directly from global fp32 (L1/L2 serves the 4x intra-block re-read).
DEVI void projQK(const float* __restrict__ X, const float* __restrict__ W,
                 const float* __restrict__ bias, char* __restrict__ dst,
                 int w, int lr, int lg) {
  f16x8 bf[2][4];
#pragma unroll
  for (int n = 0; n < 2; ++n)
#pragma unroll
    for (int kt = 0; kt < 4; ++kt)
      bf[n][kt] = ld_g8(W, w * 32 + n * 16 + lr, kt * 32 + lg * 8);
  f32x4 acc[4][2];
#pragma unroll
  for (int mt = 0; mt < 4; ++mt)
#pragma unroll
    for (int n = 0; n < 2; ++n)
      acc[mt][n] = f32x4{0.f, 0.f, 0.f, 0.f};
#pragma unroll
  for (int mt = 0; mt < 4; ++mt)
#pragma unroll
    for (int kt = 0; kt < 4; ++kt) {
      f16x8 a = ld_g8(X, mt * 16 + lr, kt * 32 + lg * 8);
      acc[mt][0] = __builtin_amdgcn_mfma_f32_16x16x32_f16(a, bf[0][kt], acc[mt][0], 0, 0, 0);
      acc[mt][1] = __builtin_amdgcn_mfma_f32_16x16x32_f16(a, bf[1][kt], acc[mt][1], 0, 0, 0);
    }
  float b0 = bias ? bias[w * 32 + lr] : 0.f;
  float b1 = bias ? bias[w * 32 + 16 + lr] : 0.f;
#pragma unroll
  for (int mt = 0; mt < 4; ++mt)
#pragma unroll
    for (int n = 0; n < 2; ++n)
#pragma unroll
      for (int r = 0; r < 4; ++r) {
        int row = mt * 16 + lg * 4 + r;   // C/D: col=lane&15, row=(lane>>4)*4+r
        int col = w * 32 + n * 16 + lr;
        *reinterpret_cast<f16*>(dst + swzA(row, col << 1)) =
            (f16)(acc[mt][n][r] + (n ? b1 : b0));
      }
}

__global__ __launch_bounds__(256, 4)
void fpca_kernel(const float* __restrict__ q_in, const float* __restrict__ k_in,
                 const float* __restrict__ v_in, const float* __restrict__ pos_in,
                 const float* __restrict__ Wq, const float* __restrict__ bq,
                 const float* __restrict__ Wk, const float* __restrict__ Wv,
                 const float* __restrict__ bv, const float* __restrict__ Wp,
                 const float* __restrict__ bp, const float* __restrict__ lsc,
                 float* __restrict__ d_x, float* __restrict__ d_attn) {
  __shared__ char smem[32768];
  const int tid = threadIdx.x;
  const int w = tid >> 6;        // wave id == head id
  const int lane = tid & 63;
  const int lr = lane & 15;
  const int lg = lane >> 4;
  const int win = blockIdx.x;
  const int b = win >> 8;
  const size_t winOff = (size_t)win << 13;  // *64*128

  // ---- Q/K projections: global X -> MFMA -> wave-private LDS cols (no barriers)
  projQK(q_in + winOff, Wq, bq, smem + R_A, w, lr, lg);
  projQK(k_in + winOff, Wk, nullptr, smem + R_B, w, lr, lg);

  // ---- S = Q_h K_h^T ----
  f16x8 aQ[4], bK[4];
#pragma unroll
  for (int t = 0; t < 4; ++t) {
    aQ[t] = ldA(smem + R_A, t * 16 + lr, w * 32 + lg * 8);
    bK[t] = ldA(smem + R_B, t * 16 + lr, w * 32 + lg * 8);
  }
  f32x4 s[4][4];
#pragma unroll
  for (int mt = 0; mt < 4; ++mt)
#pragma unroll
    for (int nt = 0; nt < 4; ++nt)
      s[mt][nt] = f32x4{0.f, 0.f, 0.f, 0.f};
#pragma unroll
  for (int mt = 0; mt < 4; ++mt)
#pragma unroll
    for (int nt = 0; nt < 4; ++nt)
      s[mt][nt] = __builtin_amdgcn_mfma_f32_16x16x32_f16(aQ[mt], bK[nt], s[mt][nt], 0, 0, 0);

  // ---- scale + position bias + softmax (rows on 16-lane groups) ----
  const float scale = exp2f(fminf(lsc[w], LOGIT_MAX_C) * L2E);
  const float* pos = pos_in + (((size_t)b * 4 + w) << 12);
#pragma unroll
  for (int mt = 0; mt < 4; ++mt)
#pragma unroll
    for (int nt = 0; nt < 4; ++nt)
#pragma unroll
      for (int r = 0; r < 4; ++r) {
        int row = mt * 16 + lg * 4 + r;
        int col = nt * 16 + lr;
        s[mt][nt][r] = s[mt][nt][r] * scale + pos[(row << 6) + col];
      }
#pragma unroll
  for (int mt = 0; mt < 4; ++mt)
#pragma unroll
    for (int r = 0; r < 4; ++r) {
      float m = fmaxf(fmaxf(s[mt][0][r], s[mt][1][r]), fmaxf(s[mt][2][r], s[mt][3][r]));
      m = fmaxf(m, __shfl_xor(m, 1));
      m = fmaxf(m, __shfl_xor(m, 2));
      m = fmaxf(m, __shfl_xor(m, 4));
      m = fmaxf(m, __shfl_xor(m, 8));
      float sum = 0.f;
#pragma unroll
      for (int nt = 0; nt < 4; ++nt) {
        float e = exp2f((s[mt][nt][r] - m) * L2E);
        s[mt][nt][r] = e;
        sum += e;
      }
      sum += __shfl_xor(sum, 1);
      sum += __shfl_xor(sum, 2);
      sum += __shfl_xor(sum, 4);
      sum += __shfl_xor(sum, 8);
      float rinv = __builtin_amdgcn_rcpf(sum);
#pragma unroll
      for (int nt = 0; nt < 4; ++nt) s[mt][nt][r] *= rinv;
    }

  __syncthreads();  // B1: all waves finished their aQ/bK LDS reads -> P may overwrite

  // ---- attn out (fp32) + P -> LDS (wave slot w*8KB over R_A|R_B) ----
  char* Pb = smem + w * 8192;
  float* attn_out = d_attn + (((size_t)win * 4 + w) << 12);
#pragma unroll
  for (int mt = 0; mt < 4; ++mt)
#pragma unroll
    for (int nt = 0; nt < 4; ++nt)
#pragma unroll
      for (int r = 0; r < 4; ++r) {
        int row = mt * 16 + lg * 4 + r;
        int col = nt * 16 + lr;
        float p = s[mt][nt][r];
        attn_out[(row << 6) + col] = p;
        *reinterpret_cast<f16*>(Pb + swzB(row, col << 1)) = (f16)p;
      }

  // hoist ALL P fragments to registers so V^T/O may overwrite the P slots
  f16x8 aP[4][2];
#pragma unroll
  for (int mt = 0; mt < 4; ++mt)
#pragma unroll
    for (int kt = 0; kt < 2; ++kt)
      aP[mt][kt] = ldB(Pb, mt * 16 + lr, kt * 32 + lg * 8);

  // ---- V projection (global X_v, results held in regs across B2) ----
  f16x8 bw[2][4];
#pragma unroll
  for (int n = 0; n < 2; ++n)
#pragma unroll
    for (int kt = 0; kt < 4; ++kt)
      bw[n][kt] = ld_g8(Wv, w * 32 + n * 16 + lr, kt * 32 + lg * 8);
  f32x4 vacc[4][2];
#pragma unroll
  for (int mt = 0; mt < 4; ++mt)
#pragma unroll
    for (int n = 0; n < 2; ++n)
      vacc[mt][n] = f32x4{0.f, 0.f, 0.f, 0.f};
#pragma unroll
  for (int mt = 0; mt < 4; ++mt)
#pragma unroll
    for (int kt = 0; kt < 4; ++kt) {
      f16x8 a = ld_g8(v_in + winOff, mt * 16 + lr, kt * 32 + lg * 8);
      vacc[mt][0] = __builtin_amdgcn_mfma_f32_16x16x32_f16(a, bw[0][kt], vacc[mt][0], 0, 0, 0);
      vacc[mt][1] = __builtin_amdgcn_mfma_f32_16x16x32_f16(a, bw[1][kt], vacc[mt][1], 0, 0, 0);
    }

  __syncthreads();  // B2: all waves hold aP in regs -> V^T/O may overwrite P slots

  // ---- V^T -> R_A [128][64] swzB (wave-private feature rows 32w..) ----
  {
    float b0 = bv[w * 32 + lr];
    float b1 = bv[w * 32 + 16 + lr];
#pragma unroll
    for (int mt = 0; mt < 4; ++mt)
#pragma unroll
      for (int n = 0; n < 2; ++n)
#pragma unroll
        for (int r = 0; r < 4; ++r) {
          int row = mt * 16 + lg * 4 + r;            // seq
          int col = w * 32 + n * 16 + lr;            // feature
          *reinterpret_cast<f16*>(smem + R_A + swzB(col, row << 1)) =
              (f16)(vacc[mt][n][r] + (n ? b1 : b0));
        }
  }

  // ---- O_h = P @ V_h ----
  f16x8 bV[2][2];
#pragma unroll
  for (int n = 0; n < 2; ++n)
#pragma unroll
    for (int kt = 0; kt < 2; ++kt)
      bV[n][kt] = ldB(smem + R_A, w * 32 + n * 16 + lr, kt * 32 + lg * 8);
  f32x4 oacc[4][2];
#pragma unroll
  for (int mt = 0; mt < 4; ++mt)
#pragma unroll
    for (int n = 0; n < 2; ++n)
      oacc[mt][n] = f32x4{0.f, 0.f, 0.f, 0.f};
#pragma unroll
  for (int mt = 0; mt < 4; ++mt)
#pragma unroll
    for (int kt = 0; kt < 2; ++kt) {
      oacc[mt][0] = __builtin_amdgcn_mfma_f32_16x16x32_f16(aP[mt][kt], bV[0][kt], oacc[mt][0], 0, 0, 0);
      oacc[mt][1] = __builtin_amdgcn_mfma_f32_16x16x32_f16(aP[mt][kt], bV[1][kt], oacc[mt][1], 0, 0, 0);
    }
  // O (merged heads) -> R_B [64][128] swzA, wave-private columns
#pragma unroll
  for (int mt = 0; mt < 4; ++mt)
#pragma unroll
    for (int n = 0; n < 2; ++n)
#pragma unroll
      for (int r = 0; r < 4; ++r) {
        int row = mt * 16 + lg * 4 + r;
        int col = w * 32 + n * 16 + lr;
        *reinterpret_cast<f16*>(smem + R_B + swzA(row, col << 1)) = (f16)oacc[mt][n][r];
      }
  __syncthreads();  // B3: all O columns written -> final proj may read all 128 cols

  // ---- x = O @ Wp^T + bp -> global fp32 ----
  f16x8 bf[2][4];
#pragma unroll
  for (int n = 0; n < 2; ++n)
#pragma unroll
    for (int kt = 0; kt < 4; ++kt)
      bf[n][kt] = ld_g8(Wp, w * 32 + n * 16 + lr, kt * 32 + lg * 8);
  f32x4 xacc[4][2];
#pragma unroll
  for (int mt = 0; mt < 4; ++mt)
#pragma unroll
    for (int n = 0; n < 2; ++n)
      xacc[mt][n] = f32x4{0.f, 0.f, 0.f, 0.f};
#pragma unroll
  for (int mt = 0; mt < 4; ++mt)
#pragma unroll
    for (int kt = 0; kt < 4; ++kt) {
      f16x8 a = ldA(smem + R_B, mt * 16 + lr, kt * 32 + lg * 8);
      xacc[mt][0] = __builtin_amdgcn_mfma_f32_16x16x32_f16(a, bf[0][kt], xacc[mt][0], 0, 0, 0);
      xacc[mt][1] = __builtin_amdgcn_mfma_f32_16x16x32_f16(a, bf[1][kt], xacc[mt][1], 0, 0, 0);
    }
  const float b0 = bp[w * 32 + lr];
  const float b1 = bp[w * 32 + 16 + lr];
  float* xo = d_x + winOff;
#pragma unroll
  for (int mt = 0; mt < 4; ++mt)
#pragma unroll
    for (int n = 0; n < 2; ++n)
#pragma unroll
      for (int r = 0; r < 4; ++r) {
        int row = mt * 16 + lg * 4 + r;
        int col = w * 32 + n * 16 + lr;
        xo[(row << 7) + col] = xacc[mt][n][r] + (n ? b1 : b0);
      }
}

extern "C" void kernel_launch(void* const* d_in, const int* in_sizes, int n_in,
                              void* d_out, int out_size, void* d_ws, size_t ws_size,
                              hipStream_t stream) {
  const float* q   = (const float*)d_in[0];
  const float* k   = (const float*)d_in[1];
  const float* v   = (const float*)d_in[2];
  const float* pos = (const float*)d_in[3];
  const float* Wq  = (const float*)d_in[4];
  const float* bq  = (const float*)d_in[5];
  const float* Wk  = (const float*)d_in[6];
  const float* Wv  = (const float*)d_in[7];
  const float* bv  = (const float*)d_in[8];
  const float* Wp  = (const float*)d_in[9];
  const float* bp  = (const float*)d_in[10];
  const float* ls  = (const float*)d_in[11];
  float* d_x    = (float*)d_out;
  float* d_attn = d_x + (size_t)16 * 16 * 16 * 64 * 128;  // 33,554,432
  fpca_kernel<<<4096, 256, 0, stream>>>(q, k, v, pos, Wq, bq, Wk, Wv, bv, Wp,
                                        bp, ls, d_x, d_attn);
}

// Round 3
// 265.689 us; speedup vs baseline: 2.0095x; 2.0095x over previous
//
#include <hip/hip_runtime.h>

using f16   = _Float16;
using f16x4 = __attribute__((ext_vector_type(4))) _Float16;
using f16x8 = __attribute__((ext_vector_type(8))) _Float16;
using f32x4 = __attribute__((ext_vector_type(4))) float;

#define DEVI __device__ __forceinline__

namespace {
// 32KB LDS, two 16KB regions, time-multiplexed (wave-private sub-slots):
//  R_A: Xq [64][128]f16 -> Q (own cols) -> Xv -> V^T [128][64] (own rows) -> O (own cols)
//  R_B: Xk [64][128]f16 -> K (own cols) -> P halves (own cols)
constexpr int R_A = 0;
constexpr int R_B = 16384;
constexpr float LOGIT_MAX_C = 4.6051701859880914f;  // log(100)
constexpr float L2E = 1.4426950408889634f;
}

// Bijective per-row XOR swizzle: conflict-free ds ops; per-row bijectivity
// preserves wave-private column ownership (disjoint cols -> disjoint bytes).
DEVI int swzA(int row, int b) { return (row << 8) + (b ^ ((row & 7) << 4)); }  // 256B rows

// Stage one 64x128 fp32 tile -> f16 swizzled LDS tile (coalesced float4 loads)
DEVI void stage_in(const float* __restrict__ src, char* __restrict__ dst, int tid) {
#pragma unroll
  for (int i = 0; i < 8; ++i) {
    int f = tid + (i << 8);          // float4 index 0..2047
    int row = f >> 5;
    float4 v = reinterpret_cast<const float4*>(src)[f];
    f16x4 h;
    h[0] = (f16)v.x; h[1] = (f16)v.y; h[2] = (f16)v.z; h[3] = (f16)v.w;
    *reinterpret_cast<f16x4*>(dst + swzA(row, (f & 31) << 3)) = h;
  }
}

DEVI f16x8 ldA(const char* base, int row, int k0) {   // [*,128] f16 tile, b128
  return *reinterpret_cast<const f16x8*>(base + swzA(row, k0 << 1));
}

// X(lds) @ W^T accumulate only (epilogue separate). W from f16 workspace (b128).
DEVI void proj_acc(const char* __restrict__ xb, const f16* __restrict__ Wm,
                   f32x4 (&acc)[4][2], int w, int lr, int lg) {
  f16x8 bf[2][4];
#pragma unroll
  for (int n = 0; n < 2; ++n)
#pragma unroll
    for (int kt = 0; kt < 4; ++kt)
      bf[n][kt] = *reinterpret_cast<const f16x8*>(Wm + (w * 32 + n * 16 + lr) * 128 +
                                                  kt * 32 + lg * 8);
#pragma unroll
  for (int mt = 0; mt < 4; ++mt)
#pragma unroll
    for (int n = 0; n < 2; ++n)
      acc[mt][n] = f32x4{0.f, 0.f, 0.f, 0.f};
#pragma unroll
  for (int mt = 0; mt < 4; ++mt)
#pragma unroll
    for (int kt = 0; kt < 4; ++kt) {
      f16x8 a = ldA(xb, mt * 16 + lr, kt * 32 + lg * 8);
      acc[mt][0] = __builtin_amdgcn_mfma_f32_16x16x32_f16(a, bf[0][kt], acc[mt][0], 0, 0, 0);
      acc[mt][1] = __builtin_amdgcn_mfma_f32_16x16x32_f16(a, bf[1][kt], acc[mt][1], 0, 0, 0);
    }
}

// C/D (col=lane&15, row=(lane>>4)*4+r) -> row-major [64][128] f16, own cols. 32 scalar u16.
DEVI void epi_rowmajor(const f32x4 (&acc)[4][2], char* __restrict__ dst,
                       const float* __restrict__ bias, int w, int lr, int lg) {
  float b0 = bias ? bias[w * 32 + lr] : 0.f;
  float b1 = bias ? bias[w * 32 + 16 + lr] : 0.f;
#pragma unroll
  for (int mt = 0; mt < 4; ++mt)
#pragma unroll
    for (int n = 0; n < 2; ++n)
#pragma unroll
      for (int r = 0; r < 4; ++r) {
        int row = mt * 16 + lg * 4 + r;
        int col = w * 32 + n * 16 + lr;
        *reinterpret_cast<f16*>(dst + swzA(row, col << 1)) =
            (f16)(acc[mt][n][r] + (n ? b1 : b0));
      }
}

// fp32 weights -> f16 workspace (Wq,Wk,Wv,Wp), 64 blocks x 256 thr x 4 elems
__global__ void wcvt_kernel(const float* __restrict__ Wq, const float* __restrict__ Wk,
                            const float* __restrict__ Wv, const float* __restrict__ Wp,
                            f16* __restrict__ W16) {
  int idx = blockIdx.x * 256 + threadIdx.x;   // 0..16383
  int m = idx >> 12;
  int off = (idx & 4095) << 2;
  const float* src = m == 0 ? Wq : m == 1 ? Wk : m == 2 ? Wv : Wp;
  float4 v = *reinterpret_cast<const float4*>(src + off);
  f16x4 h;
  h[0] = (f16)v.x; h[1] = (f16)v.y; h[2] = (f16)v.z; h[3] = (f16)v.w;
  *reinterpret_cast<f16x4*>(W16 + (m << 14) + off) = h;
}

__global__ __launch_bounds__(256, 4)
void fpca_kernel(const float* __restrict__ q_in, const float* __restrict__ k_in,
                 const float* __restrict__ v_in, const float* __restrict__ pos_in,
                 const f16* __restrict__ W16,
                 const float* __restrict__ bq, const float* __restrict__ bv,
                 const float* __restrict__ bp, const float* __restrict__ lsc,
                 float* __restrict__ d_x, float* __restrict__ d_attn) {
  __shared__ char smem[32768];
  const int tid = threadIdx.x;
  const int w = tid >> 6;        // wave id == head id
  const int lane = tid & 63;
  const int lr = lane & 15;
  const int lg = lane >> 4;
  const int win = blockIdx.x;
  const int b = win >> 8;
  const size_t winOff = (size_t)win << 13;
  const f16* Wq16 = W16;
  const f16* Wk16 = W16 + 16384;
  const f16* Wv16 = W16 + 32768;
  const f16* Wp16 = W16 + 49152;

  // ---- phase 1: stage Xq->A, Xk->B (16 float4 loads in flight) ----
  stage_in(q_in + winOff, smem + R_A, tid);
  stage_in(k_in + winOff, smem + R_B, tid);
  __syncthreads();  // BAR1

  // ---- phase 2: Q/K projection accumulators (reads A and B) ----
  f32x4 accQ[4][2], accK[4][2];
  proj_acc(smem + R_A, Wq16, accQ, w, lr, lg);
  proj_acc(smem + R_B, Wk16, accK, w, lr, lg);
  __syncthreads();  // BAR2: all A/B reads done -> epilogues may overwrite own cols

  // ---- phase 3: epilogues (own cols), hoist fragments, S^T = K Q^T ----
  epi_rowmajor(accQ, smem + R_A, bq, w, lr, lg);
  f16x8 bQ[4];
#pragma unroll
  for (int nt = 0; nt < 4; ++nt)
    bQ[nt] = ldA(smem + R_A, nt * 16 + lr, w * 32 + lg * 8);
  epi_rowmajor(accK, smem + R_B, nullptr, w, lr, lg);
  f32x4 s[4][4];
#pragma unroll
  for (int mt = 0; mt < 4; ++mt)
#pragma unroll
    for (int nt = 0; nt < 4; ++nt)
      s[mt][nt] = f32x4{0.f, 0.f, 0.f, 0.f};
#pragma unroll
  for (int mt = 0; mt < 4; ++mt) {
    f16x8 aK = ldA(smem + R_B, mt * 16 + lr, w * 32 + lg * 8);
#pragma unroll
    for (int nt = 0; nt < 4; ++nt)
      s[mt][nt] = __builtin_amdgcn_mfma_f32_16x16x32_f16(aK, bQ[nt], s[mt][nt], 0, 0, 0);
  }
  __syncthreads();  // BAR3: all bQ/aK LDS reads done -> A restageable, B rewritable

  // ---- phase 4: stage Xv->A (early); softmax on S^T; attn out; P half0 -> B ----
  stage_in(v_in + winOff, smem + R_A, tid);
  const float scale = exp2f(fminf(lsc[w], LOGIT_MAX_C) * L2E);
  const float* pos = pos_in + (((size_t)b * 4 + w) << 12);
  float* attn_out = d_attn + (((size_t)win * 4 + w) << 12);
#pragma unroll
  for (int nt = 0; nt < 4; ++nt) {
    const int q = nt * 16 + lr;   // lane's q-column; k = mt*16 + lg*4 + r (lane-local 4-runs)
#pragma unroll
    for (int mt = 0; mt < 4; ++mt) {
      float4 pv = *reinterpret_cast<const float4*>(pos + (q << 6) + mt * 16 + lg * 4);
      s[mt][nt][0] = s[mt][nt][0] * scale + pv.x;
      s[mt][nt][1] = s[mt][nt][1] * scale + pv.y;
      s[mt][nt][2] = s[mt][nt][2] * scale + pv.z;
      s[mt][nt][3] = s[mt][nt][3] * scale + pv.w;
    }
    float m = s[0][nt][0];
#pragma unroll
    for (int mt = 0; mt < 4; ++mt)
#pragma unroll
      for (int r = 0; r < 4; ++r) m = fmaxf(m, s[mt][nt][r]);
    m = fmaxf(m, __shfl_xor(m, 16));
    m = fmaxf(m, __shfl_xor(m, 32));
    float sum = 0.f;
#pragma unroll
    for (int mt = 0; mt < 4; ++mt)
#pragma unroll
      for (int r = 0; r < 4; ++r) {
        float e = exp2f((s[mt][nt][r] - m) * L2E);
        s[mt][nt][r] = e;
        sum += e;
      }
    sum += __shfl_xor(sum, 16);
    sum += __shfl_xor(sum, 32);
    float rinv = __builtin_amdgcn_rcpf(sum);
#pragma unroll
    for (int mt = 0; mt < 4; ++mt) {
      float4 o;
      o.x = (s[mt][nt][0] *= rinv);
      o.y = (s[mt][nt][1] *= rinv);
      o.z = (s[mt][nt][2] *= rinv);
      o.w = (s[mt][nt][3] *= rinv);
      *reinterpret_cast<float4*>(attn_out + (q << 6) + mt * 16 + lg * 4) = o;
    }
  }
  // P half-k tiles -> own B cols: P[q][k_local] f16, row q*256B, bytes 64w + (mt&1)*32 + lg*8
#define WR_P(MT)                                                                   \
  {                                                                                \
    _Pragma("unroll") for (int nt = 0; nt < 4; ++nt) {                             \
      const int q = nt * 16 + lr;                                                  \
      f16x4 h;                                                                     \
      h[0] = (f16)s[MT][nt][0]; h[1] = (f16)s[MT][nt][1];                          \
      h[2] = (f16)s[MT][nt][2]; h[3] = (f16)s[MT][nt][3];                          \
      *reinterpret_cast<f16x4*>(smem + R_B + (q << 8) +                            \
          ((((w) << 6) + (((MT) & 1) << 5) + (lg << 3)) ^ ((q & 7) << 4))) = h;    \
    }                                                                              \
  }
  WR_P(0)
  WR_P(1)
  __syncthreads();  // BAR4: Xv staged -> projV may read A

  // ---- phase 5: V projection accumulate (reads A) ----
  f32x4 vacc[4][2];
  proj_acc(smem + R_A, Wv16, vacc, w, lr, lg);
  __syncthreads();  // BAR5: all A reads done -> V^T may overwrite A (own rows)

  // ---- phase 6: V^T -> A (own feature rows), PV with P halves ----
  {
    float c0 = bv[w * 32 + lr], c1 = bv[w * 32 + 16 + lr];
#pragma unroll
    for (int mt = 0; mt < 4; ++mt)
#pragma unroll
      for (int n = 0; n < 2; ++n) {
        int co = w * 32 + n * 16 + lr;       // feature row of V^T [128][64]
        f16x4 h;
        h[0] = (f16)(vacc[mt][n][0] + (n ? c1 : c0));
        h[1] = (f16)(vacc[mt][n][1] + (n ? c1 : c0));
        h[2] = (f16)(vacc[mt][n][2] + (n ? c1 : c0));
        h[3] = (f16)(vacc[mt][n][3] + (n ? c1 : c0));
        *reinterpret_cast<f16x4*>(smem + R_A + (co << 7) +
            (((mt << 5) + (lg << 3)) ^ ((co & 7) << 4))) = h;
      }
  }
  f16x8 bV[2][2];
#pragma unroll
  for (int n = 0; n < 2; ++n)
#pragma unroll
    for (int kt = 0; kt < 2; ++kt) {
      int d = w * 32 + n * 16 + lr;
      bV[n][kt] = *reinterpret_cast<const f16x8*>(smem + R_A + (d << 7) +
          (((kt << 6) + (lg << 4)) ^ ((d & 7) << 4)));
    }
  f32x4 oacc[4][2];
#pragma unroll
  for (int mt = 0; mt < 4; ++mt)
#pragma unroll
    for (int n = 0; n < 2; ++n)
      oacc[mt][n] = f32x4{0.f, 0.f, 0.f, 0.f};
#pragma unroll
  for (int mt = 0; mt < 4; ++mt) {   // kt = 0 (P half0, k 0..31)
    int q = mt * 16 + lr;
    f16x8 aP = *reinterpret_cast<const f16x8*>(smem + R_B + (q << 8) +
        (((w << 6) + (lg << 4)) ^ ((q & 7) << 4)));
    oacc[mt][0] = __builtin_amdgcn_mfma_f32_16x16x32_f16(aP, bV[0][0], oacc[mt][0], 0, 0, 0);
    oacc[mt][1] = __builtin_amdgcn_mfma_f32_16x16x32_f16(aP, bV[1][0], oacc[mt][1], 0, 0, 0);
  }
  WR_P(2)
  WR_P(3)
#pragma unroll
  for (int mt = 0; mt < 4; ++mt) {   // kt = 1 (P half1, k 32..63)
    int q = mt * 16 + lr;
    f16x8 aP = *reinterpret_cast<const f16x8*>(smem + R_B + (q << 8) +
        (((w << 6) + (lg << 4)) ^ ((q & 7) << 4)));
    oacc[mt][0] = __builtin_amdgcn_mfma_f32_16x16x32_f16(aP, bV[0][1], oacc[mt][0], 0, 0, 0);
    oacc[mt][1] = __builtin_amdgcn_mfma_f32_16x16x32_f16(aP, bV[1][1], oacc[mt][1], 0, 0, 0);
  }
  __syncthreads();  // BAR6: all bV reads done -> O may overwrite A (own cols)

  // ---- phase 7: O -> A (merged heads, own cols) ----
  epi_rowmajor(oacc, smem + R_A, nullptr, w, lr, lg);
  __syncthreads();  // BAR7: all O cols written -> final proj reads all 128

  // ---- phase 8: x = O @ Wp^T + bp -> global fp32 ----
  f16x8 bf[2][4];
#pragma unroll
  for (int n = 0; n < 2; ++n)
#pragma unroll
    for (int kt = 0; kt < 4; ++kt)
      bf[n][kt] = *reinterpret_cast<const f16x8*>(Wp16 + (w * 32 + n * 16 + lr) * 128 +
                                                  kt * 32 + lg * 8);
  f32x4 xacc[4][2];
#pragma unroll
  for (int mt = 0; mt < 4; ++mt)
#pragma unroll
    for (int n = 0; n < 2; ++n)
      xacc[mt][n] = f32x4{0.f, 0.f, 0.f, 0.f};
#pragma unroll
  for (int mt = 0; mt < 4; ++mt)
#pragma unroll
    for (int kt = 0; kt < 4; ++kt) {
      f16x8 a = ldA(smem + R_A, mt * 16 + lr, kt * 32 + lg * 8);
      xacc[mt][0] = __builtin_amdgcn_mfma_f32_16x16x32_f16(a, bf[0][kt], xacc[mt][0], 0, 0, 0);
      xacc[mt][1] = __builtin_amdgcn_mfma_f32_16x16x32_f16(a, bf[1][kt], xacc[mt][1], 0, 0, 0);
    }
  const float b0 = bp[w * 32 + lr];
  const float b1 = bp[w * 32 + 16 + lr];
  float* xo = d_x + winOff;
#pragma unroll
  for (int mt = 0; mt < 4; ++mt)
#pragma unroll
    for (int n = 0; n < 2; ++n)
#pragma unroll
      for (int r = 0; r < 4; ++r) {
        int row = mt * 16 + lg * 4 + r;
        int col = w * 32 + n * 16 + lr;
        xo[(row << 7) + col] = xacc[mt][n][r] + (n ? b1 : b0);
      }
}

extern "C" void kernel_launch(void* const* d_in, const int* in_sizes, int n_in,
                              void* d_out, int out_size, void* d_ws, size_t ws_size,
                              hipStream_t stream) {
  const float* q   = (const float*)d_in[0];
  const float* k   = (const float*)d_in[1];
  const float* v   = (const float*)d_in[2];
  const float* pos = (const float*)d_in[3];
  const float* Wq  = (const float*)d_in[4];
  const float* bq  = (const float*)d_in[5];
  const float* Wk  = (const float*)d_in[6];
  const float* Wv  = (const float*)d_in[7];
  const float* bv  = (const float*)d_in[8];
  const float* Wp  = (const float*)d_in[9];
  const float* bp  = (const float*)d_in[10];
  const float* ls  = (const float*)d_in[11];
  f16* W16 = (f16*)d_ws;   // 4 x 128 x 128 f16 = 128KB
  float* d_x    = (float*)d_out;
  float* d_attn = d_x + (size_t)16 * 16 * 16 * 64 * 128;  // 33,554,432
  wcvt_kernel<<<64, 256, 0, stream>>>(Wq, Wk, Wv, Wp, W16);
  fpca_kernel<<<4096, 256, 0, stream>>>(q, k, v, pos, W16, bq, bv, bp, ls,
                                        d_x, d_attn);
}